// Round 1
// baseline (598.156 us; speedup 1.0000x reference)
//
#include <hip/hip_runtime.h>
#include <stdint.h>
#include <stddef.h>

// Problem constants (DINOv2 self-attention)
#define SQ     1370              // sequence length
#define NBATCH 8
#define NHEADS 16
#define DH     64                // head dim
#define DM     1024              // model dim
#define MROWS  (NBATCH * SQ)     // 10960 flattened rows

typedef _Float16 f16;
typedef __attribute__((ext_vector_type(8))) _Float16 f16x8;
typedef __attribute__((ext_vector_type(4))) _Float16 f16x4;
typedef __attribute__((ext_vector_type(4))) float    f32x4;

#define MFMA_16x16x32_F16(a, b, c) __builtin_amdgcn_mfma_f32_16x16x32_f16((a), (b), (c), 0, 0, 0)

// ---------------------------------------------------------------------------
// Kernel 1: fused QKV projection GEMM.
//   out[m,n] = sum_k hs[m,k] * W[n,k] + bias[n]   (torch Linear: x @ W^T + b)
// A = hs [MROWS, DM] fp32 row-major; B = W [DM, DM] fp32 row-major (B^T GEMM).
// fp32 -> f16 conversion happens during LDS staging.
// Output scattered into [B, H, S, DH] f16 layout for the attention kernel.
// Tile: 128x128, BK=32, 256 threads = 4 waves (2x2 of 64x64 per-wave tiles).
// blockIdx.z in {0,1,2} selects Q/K/V weight+bias+dst.
// ---------------------------------------------------------------------------
__global__ __launch_bounds__(256) void qkv_gemm_kernel(
    const float* __restrict__ hs,
    const float* __restrict__ Wq, const float* __restrict__ bq,
    const float* __restrict__ Wk, const float* __restrict__ bk,
    const float* __restrict__ Wv, const float* __restrict__ bv,
    f16* __restrict__ Qo, f16* __restrict__ Ko, f16* __restrict__ Vo)
{
    // LDS tiles padded to 40 f16/row (80 B): rows stay 16B-aligned for
    // ds_read_b128; bank aliasing on frag reads is 2-way (free, m136).
    __shared__ f16 As[128][40];
    __shared__ f16 Bs[128][40];

    const float* W; const float* bias; f16* outp;
    if (blockIdx.z == 0)      { W = Wq; bias = bq; outp = Qo; }
    else if (blockIdx.z == 1) { W = Wk; bias = bk; outp = Ko; }
    else                      { W = Wv; bias = bv; outp = Vo; }

    const int m0   = blockIdx.x * 128;
    const int n0   = blockIdx.y * 128;
    const int t    = threadIdx.x;
    const int lane = t & 63;
    const int wid  = t >> 6;
    const int wm   = (wid >> 1) * 64;   // wave tile origin in M
    const int wn   = (wid & 1) * 64;    // wave tile origin in N
    const int lr   = lane & 15;
    const int quad = lane >> 4;

    f32x4 acc[4][4];
#pragma unroll
    for (int i = 0; i < 4; i++)
#pragma unroll
        for (int j = 0; j < 4; j++) acc[i][j] = (f32x4){0.f, 0.f, 0.f, 0.f};

    // Staging assignment: 8 threads per row (4 floats each), 32 rows/round.
    const int srow = t >> 3;        // 0..31
    const int scol = (t & 7) * 4;   // 0,4,...,28

    for (int k0 = 0; k0 < DM; k0 += 32) {
        __syncthreads();
#pragma unroll
        for (int rr = 0; rr < 4; rr++) {
            const int row = rr * 32 + srow;
            int gm = m0 + row; if (gm >= MROWS) gm = MROWS - 1;  // clamp tail
            const float4 va = *(const float4*)(hs + (size_t)gm * DM + k0 + scol);
            f16x4 ha; ha.x = (f16)va.x; ha.y = (f16)va.y; ha.z = (f16)va.z; ha.w = (f16)va.w;
            *(f16x4*)&As[row][scol] = ha;
            const float4 vb = *(const float4*)(W + (size_t)(n0 + row) * DM + k0 + scol);
            f16x4 hb; hb.x = (f16)vb.x; hb.y = (f16)vb.y; hb.z = (f16)vb.z; hb.w = (f16)vb.w;
            *(f16x4*)&Bs[row][scol] = hb;
        }
        __syncthreads();

        // A-frag: lane holds row (lane&15), k = quad*8..+7 (16x16x32 layout)
        // B-frag: lane holds col (lane&15), k = quad*8..+7
        f16x8 af[4], bf[4];
#pragma unroll
        for (int i = 0; i < 4; i++) {
            af[i] = *(const f16x8*)&As[wm + i * 16 + lr][quad * 8];
            bf[i] = *(const f16x8*)&Bs[wn + i * 16 + lr][quad * 8];
        }
#pragma unroll
        for (int i = 0; i < 4; i++)
#pragma unroll
            for (int j = 0; j < 4; j++)
                acc[i][j] = MFMA_16x16x32_F16(af[i], bf[j], acc[i][j]);
    }

    // Epilogue: C/D layout row = quad*4+reg, col = lane&15 (m89-verified).
    // Scatter to [B, H, S, DH] f16.
#pragma unroll
    for (int j = 0; j < 4; j++) {
        const int n  = n0 + wn + j * 16 + lr;
        const float bv_ = bias[n];
        const int h = n >> 6, d = n & 63;
#pragma unroll
        for (int i = 0; i < 4; i++) {
#pragma unroll
            for (int r = 0; r < 4; r++) {
                const int m = m0 + wm + i * 16 + quad * 4 + r;
                if (m < MROWS) {
                    const int b = m / SQ, s = m % SQ;
                    outp[(((size_t)(b * NHEADS + h)) * SQ + s) * DH + d] =
                        (f16)(acc[i][j][r] + bv_);
                }
            }
        }
    }
}

// ---------------------------------------------------------------------------
// Kernel 2: flash-style attention.
// Grid: (ceil(SQ/64), B*H). Block: 256 = 4 waves; wave owns 16 q-rows.
// Q,K fragments read directly from global (contiguous 16B per lane).
// V staged transposed into LDS (Vt[d][n], stride 72) for PV B-fragments.
// P (scores->probs) round-trips through wave-private LDS: C-layout -> A-layout.
// Online softmax (m,l per q-row) in fp32; tail keys masked to -inf.
// ---------------------------------------------------------------------------
__global__ __launch_bounds__(256) void attn_kernel(
    const f16* __restrict__ Q,   // [B*H, SQ, DH]
    const f16* __restrict__ K,
    const f16* __restrict__ V,
    float* __restrict__ out)     // [B, SQ, DM]
{
    __shared__ f16 Vt[DH][72];        // V transposed: [d][n], padded stride
    __shared__ f16 Pl[4][16][72];     // per-wave P tile, padded stride

    const int q0   = blockIdx.x * 64;
    const int bh   = blockIdx.y;
    const int b    = bh >> 4;
    const int h    = bh & 15;
    const int t    = threadIdx.x;
    const int lane = t & 63;
    const int wid  = t >> 6;
    const int lr   = lane & 15;
    const int quad = lane >> 4;

    const f16* Qb = Q + (size_t)bh * SQ * DH;
    const f16* Kb = K + (size_t)bh * SQ * DH;
    const f16* Vb = V + (size_t)bh * SQ * DH;

    // Q A-fragments for this wave's 16 rows: row = lane&15, k = kk*32+quad*8
    int qrow = q0 + wid * 16 + lr;
    const int qrow_c = (qrow < SQ) ? qrow : (SQ - 1);   // clamp tail rows
    f16x8 qf[2];
    qf[0] = *(const f16x8*)(Qb + (size_t)qrow_c * DH + quad * 8);
    qf[1] = *(const f16x8*)(Qb + (size_t)qrow_c * DH + 32 + quad * 8);

    f32x4 o[4];
#pragma unroll
    for (int i = 0; i < 4; i++) o[i] = (f32x4){0.f, 0.f, 0.f, 0.f};
    float mrun[4], lrun[4];
#pragma unroll
    for (int r = 0; r < 4; r++) { mrun[r] = -__builtin_inff(); lrun[r] = 0.f; }

    const int vrow = t >> 3;        // 0..31 (V staging: 8 threads per key row)
    const int vcol = (t & 7) * 8;   // 0..56

    for (int j0 = 0; j0 < SQ; j0 += 64) {
        __syncthreads();            // protect previous iter's Vt reads
        // Stage V tile transposed: Vt[d][n] = V[j0+n][d]
#pragma unroll
        for (int rr = 0; rr < 2; rr++) {
            const int n = rr * 32 + vrow;
            int gn = j0 + n; if (gn >= SQ) gn = SQ - 1;   // clamped; P=0 there
            const f16x8 vv = *(const f16x8*)(Vb + (size_t)gn * DH + vcol);
#pragma unroll
            for (int j = 0; j < 8; j++) Vt[vcol + j][n] = vv[j];
        }
        __syncthreads();

        // Scores: S = Q K^T * 0.125 ; C-layout row=quad*4+reg, col=lane&15
        float sc[4][4];   // [nb][reg]
#pragma unroll
        for (int nb = 0; nb < 4; nb++) {
            const int krow = j0 + nb * 16 + lr;
            const int krow_c = (krow < SQ) ? krow : (SQ - 1);
            const f16x8 kf0 = *(const f16x8*)(Kb + (size_t)krow_c * DH + quad * 8);
            const f16x8 kf1 = *(const f16x8*)(Kb + (size_t)krow_c * DH + 32 + quad * 8);
            f32x4 s = (f32x4){0.f, 0.f, 0.f, 0.f};
            s = MFMA_16x16x32_F16(qf[0], kf0, s);
            s = MFMA_16x16x32_F16(qf[1], kf1, s);
            const bool valid = (j0 + nb * 16 + lr) < SQ;   // key-col mask
#pragma unroll
            for (int r = 0; r < 4; r++)
                sc[nb][r] = valid ? s[r] * 0.125f : -__builtin_inff();
        }

        // Online softmax per row (rows = quad*4+r; reduce across quad's 16 lanes)
        float mnew[4], alpha[4];
#pragma unroll
        for (int r = 0; r < 4; r++) {
            float pm = fmaxf(fmaxf(sc[0][r], sc[1][r]), fmaxf(sc[2][r], sc[3][r]));
#pragma unroll
            for (int off = 1; off < 16; off <<= 1)
                pm = fmaxf(pm, __shfl_xor(pm, off, 64));
            mnew[r]  = fmaxf(mrun[r], pm);
            alpha[r] = __expf(mrun[r] - mnew[r]);   // first iter: exp(-inf)=0
            mrun[r]  = mnew[r];
        }
#pragma unroll
        for (int nb = 0; nb < 4; nb++)
#pragma unroll
            for (int r = 0; r < 4; r++)
                sc[nb][r] = __expf(sc[nb][r] - mnew[r]);   // -inf -> 0 (masked)
#pragma unroll
        for (int r = 0; r < 4; r++) {
            float rs = sc[0][r] + sc[1][r] + sc[2][r] + sc[3][r];
#pragma unroll
            for (int off = 1; off < 16; off <<= 1)
                rs += __shfl_xor(rs, off, 64);
            lrun[r] = lrun[r] * alpha[r] + rs;
        }
#pragma unroll
        for (int d = 0; d < 4; d++)
#pragma unroll
            for (int r = 0; r < 4; r++)
                o[d][r] *= alpha[r];

        // P: C-layout -> LDS -> A-layout (wave-private region, no barrier)
#pragma unroll
        for (int nb = 0; nb < 4; nb++)
#pragma unroll
            for (int r = 0; r < 4; r++)
                Pl[wid][quad * 4 + r][nb * 16 + lr] = (f16)sc[nb][r];

        const f16x8 pf0 = *(const f16x8*)&Pl[wid][lr][quad * 8];
        const f16x8 pf1 = *(const f16x8*)&Pl[wid][lr][32 + quad * 8];
#pragma unroll
        for (int d = 0; d < 4; d++) {
            const f16x8 vf0 = *(const f16x8*)&Vt[d * 16 + lr][quad * 8];
            const f16x8 vf1 = *(const f16x8*)&Vt[d * 16 + lr][32 + quad * 8];
            o[d] = MFMA_16x16x32_F16(pf0, vf0, o[d]);
            o[d] = MFMA_16x16x32_F16(pf1, vf1, o[d]);
        }
    }

    // Epilogue: normalize and write fp32 [B, S, H*DH]
#pragma unroll
    for (int r = 0; r < 4; r++) {
        const int srow_q = q0 + wid * 16 + quad * 4 + r;
        if (srow_q < SQ) {
            const float inv = 1.0f / lrun[r];
#pragma unroll
            for (int d = 0; d < 4; d++)
                out[((size_t)(b * SQ + srow_q)) * DM + h * DH + d * 16 + lr] =
                    o[d][r] * inv;
        }
    }
}

// ---------------------------------------------------------------------------
extern "C" void kernel_launch(void* const* d_in, const int* in_sizes, int n_in,
                              void* d_out, int out_size, void* d_ws, size_t ws_size,
                              hipStream_t stream) {
    const float* hs = (const float*)d_in[0];
    const float* Wq = (const float*)d_in[1];
    const float* bq = (const float*)d_in[2];
    const float* Wk = (const float*)d_in[3];
    const float* bk = (const float*)d_in[4];
    const float* Wv = (const float*)d_in[5];
    const float* bv = (const float*)d_in[6];
    float* out = (float*)d_out;

    // Workspace: Q,K,V f16 [B,H,S,DH] = 3 * 11,223,040 elems = 67,338,240 B
    const size_t qkv_elems = (size_t)NBATCH * NHEADS * SQ * DH;
    f16* Qw = (f16*)d_ws;
    f16* Kw = Qw + qkv_elems;
    f16* Vw = Kw + qkv_elems;

    dim3 ggemm((MROWS + 127) / 128, DM / 128, 3);   // (86, 8, 3)
    qkv_gemm_kernel<<<ggemm, 256, 0, stream>>>(hs, Wq, bq, Wk, bk, Wv, bv,
                                               Qw, Kw, Vw);

    dim3 gattn((SQ + 63) / 64, NBATCH * NHEADS);    // (22, 128)
    attn_kernel<<<gattn, 256, 0, stream>>>(Qw, Kw, Vw, out);
}